// Round 2
// baseline (762.313 us; speedup 1.0000x reference)
//
#include <hip/hip_runtime.h>
#include <hip/hip_bf16.h>

// AttentionLayer, B=8, QN=KN=2048, DIN=DPROJ=1024. ALL float tensors are f32
// (threshold arithmetic: 2.33e-3 = 2% of ref absmax, no bf16 floor applied).
// Internally compute in bf16 MFMA (2% rel threshold >> bf16 GEMM error).
//   Pq  = query·Wq^T + bq   (f32 in -> bf16 out, ws)
//   Pk  = key·Wk^T + bk     (f32 in -> bf16 out, ws)
//   PvT = (value·Wv^T+bv)^T (f32 in -> bf16 out, ws)  [transposed for B^T ctx GEMM]
//   S   = Pq·Pk^T / 32      (bf16 in -> f32 out, d_out attn region)
//   softmax+mask in place (f32) + bf16 copy attnb -> ws (aliases dead Pq/Pk)
//   ctx = attnb·Pv          (bf16 in -> f32 out, d_out ctx region)

typedef __bf16 bf16;
typedef __bf16 bf16x4 __attribute__((ext_vector_type(4)));
typedef __bf16 bf16x8 __attribute__((ext_vector_type(8)));
typedef float f32x4 __attribute__((ext_vector_type(4)));

#define TILE 128
#define BK 32

__device__ __forceinline__ void gld_lds16(const bf16* g, bf16* l) {
  __builtin_amdgcn_global_load_lds(
      (const __attribute__((address_space(1))) void*)g,
      (__attribute__((address_space(3))) void*)l, 16, 0, 0);
}

// ---------------- GEMM A: f32 inputs, bf16 output (projections) ----------------
// C[m][n] = sum_k A[m][k]*Bt[n][k] + bias   (bias_mode: 1 = bias[n], 2 = bias[m])
__global__ __launch_bounds__(256, 2)
void gemm_f32in(const float* __restrict__ A, int lda,
                const float* __restrict__ Bt, int ldb,
                bf16* __restrict__ C, int ldc,
                const float* __restrict__ bias, int bias_mode, int K)
{
  __shared__ bf16 As[TILE * BK];
  __shared__ bf16 Bs[TILE * BK];
  const int tid = threadIdx.x;
  const int wave = tid >> 6, lane = tid & 63;
  const int wm = (wave >> 1) * 64, wn = (wave & 1) * 64;
  const long m0 = (long)blockIdx.x * TILE;
  const long n0 = (long)blockIdx.y * TILE;

  f32x4 acc[4][4] = {};
  const int fr = lane & 15, fq = lane >> 4;

  for (int k0 = 0; k0 < K; k0 += BK) {
    __syncthreads();
#pragma unroll
    for (int j = 0; j < 4; ++j) {
      int c = j * 256 + tid;            // 1024 chunks of 4 f32 per matrix
      int row = c >> 3, col = (c & 7) * 4;
      f32x4 av = *(const f32x4*)&A[(m0 + row) * (long)lda + k0 + col];
      f32x4 bv = *(const f32x4*)&Bt[(n0 + row) * (long)ldb + k0 + col];
      bf16x4 ab, bb;
      ab[0] = (bf16)av[0]; ab[1] = (bf16)av[1]; ab[2] = (bf16)av[2]; ab[3] = (bf16)av[3];
      bb[0] = (bf16)bv[0]; bb[1] = (bf16)bv[1]; bb[2] = (bf16)bv[2]; bb[3] = (bf16)bv[3];
      *(bf16x4*)&As[row * BK + col] = ab;
      *(bf16x4*)&Bs[row * BK + col] = bb;
    }
    __syncthreads();

    bf16x8 af[4], bg[4];
#pragma unroll
    for (int i = 0; i < 4; ++i)
      af[i] = *(const bf16x8*)&As[(wm + i * 16 + fr) * BK + fq * 8];
#pragma unroll
    for (int i = 0; i < 4; ++i)
      bg[i] = *(const bf16x8*)&Bs[(wn + i * 16 + fr) * BK + fq * 8];
#pragma unroll
    for (int mi = 0; mi < 4; ++mi)
#pragma unroll
      for (int ni = 0; ni < 4; ++ni)
        acc[mi][ni] = __builtin_amdgcn_mfma_f32_16x16x32_bf16(
            af[mi], bg[ni], acc[mi][ni], 0, 0, 0);
  }

  const int cc = lane & 15, cq = lane >> 4;  // C/D: col=lane&15, row=quad*4+reg
#pragma unroll
  for (int mi = 0; mi < 4; ++mi)
#pragma unroll
    for (int ni = 0; ni < 4; ++ni)
#pragma unroll
      for (int r = 0; r < 4; ++r) {
        int row = wm + mi * 16 + cq * 4 + r;
        int col = wn + ni * 16 + cc;
        float v = acc[mi][ni][r];
        if (bias_mode == 1) v += bias[n0 + col];
        else if (bias_mode == 2) v += bias[m0 + row];
        C[(m0 + row) * (long)ldc + (n0 + col)] = (bf16)v;
      }
}

// ---------------- GEMM B: bf16 inputs (global_load_lds), f32 output ----------------
__global__ __launch_bounds__(256, 2)
void gemm_bf16(const bf16* __restrict__ A, int lda, long sA,
               const bf16* __restrict__ Bt, int ldb, long sB,
               float* __restrict__ C, int ldc, long sC,
               int K, float scale)
{
  __shared__ bf16 As[TILE * BK];
  __shared__ bf16 Bs[TILE * BK];
  const int tid = threadIdx.x;
  const int wave = tid >> 6, lane = tid & 63;
  const int wm = (wave >> 1) * 64, wn = (wave & 1) * 64;
  const long m0 = (long)blockIdx.x * TILE;
  const long n0 = (long)blockIdx.y * TILE;
  A  += (long)blockIdx.z * sA;
  Bt += (long)blockIdx.z * sB;
  C  += (long)blockIdx.z * sC;

  f32x4 acc[4][4] = {};

  const int srow = tid >> 2;
  const int scol = (tid & 3) * 8;
  const bf16* Ag0 = A  + (m0 + srow) * (long)lda + scol;
  const bf16* Ag1 = A  + (m0 + 64 + srow) * (long)lda + scol;
  const bf16* Bg0 = Bt + (n0 + srow) * (long)ldb + scol;
  const bf16* Bg1 = Bt + (n0 + 64 + srow) * (long)ldb + scol;
  bf16* Al0 = &As[tid * 8];
  bf16* Al1 = &As[(256 + tid) * 8];
  bf16* Bl0 = &Bs[tid * 8];
  bf16* Bl1 = &Bs[(256 + tid) * 8];

  const int fr = lane & 15, fq = lane >> 4;

  for (int k0 = 0; k0 < K; k0 += BK) {
    __syncthreads();
    gld_lds16(Ag0 + k0, Al0);
    gld_lds16(Ag1 + k0, Al1);
    gld_lds16(Bg0 + k0, Bl0);
    gld_lds16(Bg1 + k0, Bl1);
    __syncthreads();

    bf16x8 af[4], bg[4];
#pragma unroll
    for (int i = 0; i < 4; ++i)
      af[i] = *(const bf16x8*)&As[(wm + i * 16 + fr) * BK + fq * 8];
#pragma unroll
    for (int i = 0; i < 4; ++i)
      bg[i] = *(const bf16x8*)&Bs[(wn + i * 16 + fr) * BK + fq * 8];
#pragma unroll
    for (int mi = 0; mi < 4; ++mi)
#pragma unroll
      for (int ni = 0; ni < 4; ++ni)
        acc[mi][ni] = __builtin_amdgcn_mfma_f32_16x16x32_bf16(
            af[mi], bg[ni], acc[mi][ni], 0, 0, 0);
  }

  const int cc = lane & 15, cq = lane >> 4;
#pragma unroll
  for (int mi = 0; mi < 4; ++mi)
#pragma unroll
    for (int ni = 0; ni < 4; ++ni)
#pragma unroll
      for (int r = 0; r < 4; ++r) {
        int row = wm + mi * 16 + cq * 4 + r;
        int col = wn + ni * 16 + cc;
        C[(m0 + row) * (long)ldc + (n0 + col)] = acc[mi][ni][r] * scale;
      }
}

// ---------------- masked softmax: f32 in-place + bf16 copy ----------------
__global__ __launch_bounds__(256)
void softmax_mask(const int* __restrict__ mask, float* __restrict__ attn,
                  bf16* __restrict__ attnb)
{
  const int row = blockIdx.x;            // b*2048 + q
  const int b = row >> 11;
  float* arow = attn + (long)row * 2048;
  bf16* brow = attnb + (long)row * 2048;
  const int* mrow = mask + (b << 11);
  const int tid = threadIdx.x;
  const int lane = tid & 63, wave = tid >> 6;

  f32x4 s[2];
  int4 mk[2];
  s[0] = *(const f32x4*)&arow[tid * 4];
  s[1] = *(const f32x4*)&arow[1024 + tid * 4];
  mk[0] = *(const int4*)&mrow[tid * 4];
  mk[1] = *(const int4*)&mrow[1024 + tid * 4];
  const int m[8] = {mk[0].x, mk[0].y, mk[0].z, mk[0].w,
                    mk[1].x, mk[1].y, mk[1].z, mk[1].w};

  float mx = -3e38f;
#pragma unroll
  for (int i = 0; i < 8; ++i)
    if (m[i]) mx = fmaxf(mx, s[i >> 2][i & 3]);
#pragma unroll
  for (int off = 32; off > 0; off >>= 1) mx = fmaxf(mx, __shfl_xor(mx, off));
  __shared__ float rmax[4], rsum[4];
  if (lane == 0) rmax[wave] = mx;
  __syncthreads();
  mx = fmaxf(fmaxf(rmax[0], rmax[1]), fmaxf(rmax[2], rmax[3]));

  float e[8], sum = 0.f;
#pragma unroll
  for (int i = 0; i < 8; ++i) {
    e[i] = m[i] ? __expf(s[i >> 2][i & 3] - mx) : 0.f;
    sum += e[i];
  }
#pragma unroll
  for (int off = 32; off > 0; off >>= 1) sum += __shfl_xor(sum, off);
  if (lane == 0) rsum[wave] = sum;
  __syncthreads();
  sum = rsum[0] + rsum[1] + rsum[2] + rsum[3];
  float inv = sum > 0.f ? 1.f / sum : 0.f;

  f32x4 o; bf16x4 ob;
#pragma unroll
  for (int h = 0; h < 2; ++h) {
#pragma unroll
    for (int i = 0; i < 4; ++i) {
      float v = e[h * 4 + i] * inv;
      o[i] = v; ob[i] = (bf16)v;
    }
    *(f32x4*)&arow[h * 1024 + tid * 4] = o;
    *(bf16x4*)&brow[h * 1024 + tid * 4] = ob;
  }
}

extern "C" void kernel_launch(void* const* d_in, const int* in_sizes, int n_in,
                              void* d_out, int out_size, void* d_ws, size_t ws_size,
                              hipStream_t stream)
{
  const float* query = (const float*)d_in[0];
  const float* key   = (const float*)d_in[1];
  const float* value = (const float*)d_in[2];
  const int*   mask  = (const int*)d_in[3];
  const float* Wq = (const float*)d_in[4];
  const float* bq = (const float*)d_in[5];
  const float* Wk = (const float*)d_in[6];
  const float* bk = (const float*)d_in[7];
  const float* Wv = (const float*)d_in[8];
  const float* bv = (const float*)d_in[9];

  float* ctx  = (float*)d_out;                       // [8][2048][1024] f32
  float* attn = ctx + (size_t)8 * 2048 * 1024;       // [8][2048][2048] f32

  // ws layout (96 MiB): Pq [0,32M), Pk [32M,64M), PvT [64M,96M) (bf16)
  // attnb (64 MiB bf16) aliases Pq+Pk after they are dead.
  bf16* Pq    = (bf16*)d_ws;
  bf16* Pk    = Pq + (size_t)16384 * 1024;
  bf16* PvT   = Pk + (size_t)16384 * 1024;
  bf16* attnb = (bf16*)d_ws;

  dim3 blk(256);

  // Pq = query·Wq^T + bq
  hipLaunchKernelGGL(gemm_f32in, dim3(128, 8), blk, 0, stream,
      query, 1024, Wq, 1024, Pq, 1024, bq, 1, 1024);
  // Pk = key·Wk^T + bk
  hipLaunchKernelGGL(gemm_f32in, dim3(128, 8), blk, 0, stream,
      key, 1024, Wk, 1024, Pk, 1024, bk, 1, 1024);
  // PvT[d][i] = sum_c Wv[d][c]*value[i][c] + bv[d]
  hipLaunchKernelGGL(gemm_f32in, dim3(8, 128), blk, 0, stream,
      Wv, 1024, value, 1024, PvT, 16384, bv, 2, 1024);
  // raw scores (f32) -> attn region, scale 1/32
  hipLaunchKernelGGL(gemm_bf16, dim3(16, 16, 8), blk, 0, stream,
      Pq, 1024, (long)2048 * 1024, Pk, 1024, (long)2048 * 1024,
      attn, 2048, (long)2048 * 2048, 1024, 0.03125f);
  // masked softmax in place + bf16 copy
  hipLaunchKernelGGL(softmax_mask, dim3(16384), blk, 0, stream, mask, attn, attnb);
  // ctx = attnb·Pv
  hipLaunchKernelGGL(gemm_bf16, dim3(16, 8, 8), blk, 0, stream,
      attnb, 2048, (long)2048 * 2048, PvT, 16384, 2048L,
      ctx, 1024, (long)2048 * 1024, 2048, 1.0f);
}